// Round 1
// 326.304 us; speedup vs baseline: 1.0198x; 1.0198x over previous
//
#include <hip/hip_runtime.h>
#include <hip/hip_bf16.h>

// Problem constants
#define NB   4
#define SEQ  2048
#define DMODEL 1024
#define NHEAD 16
#define HDIM 64
#define MROWS (NB * SEQ)          // 8192
#define N_QKV (3 * DMODEL)        // 3072

typedef __attribute__((ext_vector_type(8))) short bf16x8;
typedef __attribute__((ext_vector_type(4))) float f32x4;

#define MFMA16(a, b, c) __builtin_amdgcn_mfma_f32_16x16x32_bf16((a), (b), (c), 0, 0, 0)

// single 16B load (global: global_load_dwordx4; LDS: ds_read_b128)
__device__ inline bf16x8 load16(const __hip_bfloat16* p) {
    union { uint4 u; bf16x8 v; } t;
    t.u = *(const uint4*)p;
    return t.v;
}

// fp32 -> bf16 raw bits, round-to-nearest-even
__device__ inline ushort f2bf(float f) {
    union { float f; unsigned int u; } a;
    a.f = f;
    unsigned int r = a.u + 0x7FFFu + ((a.u >> 16) & 1u);
    return (ushort)(r >> 16);
}

// HW pack: 2 f32 -> 2 bf16 in one u32 (lo -> low half). No builtin on gfx950.
__device__ inline unsigned int cvt_pk_bf16(float lo, float hi) {
    unsigned int r;
    asm("v_cvt_pk_bf16_f32 %0, %1, %2" : "=v"(r) : "v"(lo), "v"(hi));
    return r;
}

// async global->LDS, 16B per lane
__device__ inline void gload_lds16(const __hip_bfloat16* g, __hip_bfloat16* l) {
    __builtin_amdgcn_global_load_lds(
        (const __attribute__((address_space(1))) unsigned int*)g,
        (__attribute__((address_space(3))) unsigned int*)l,
        16, 0, 0);
}

// ---------------- cast fp32 -> bf16 (first scale_n elements scaled by sc) ----------------
__global__ __launch_bounds__(256)
void cast_bf16_kernel(const float* __restrict__ in, ushort* __restrict__ out, int n,
                      int scale_n, float sc) {
    int idx = (blockIdx.x * 256 + threadIdx.x) * 4;
    if (idx + 3 < n) {
        float4 v = *(const float4*)(in + idx);
        float s = (idx < scale_n) ? sc : 1.0f;
        ushort4 o;
        o.x = f2bf(v.x * s);
        o.y = f2bf(v.y * s);
        o.z = f2bf(v.z * s);
        o.w = f2bf(v.w * s);
        *(ushort4*)(out + idx) = o;
    }
}

// ---------------- C[M,N] = A[M,K] * B[N,K]^T  (bf16 in, f32 acc) ----------------
// MODE 1: f32 plain output (N==DMODEL).
// MODE 2: QKV — regions: Q[8192x1024] | K[8192x1024] | V^T[64bh][64d][2048s].
template<int MODE>
__global__ __launch_bounds__(256)
void gemm_bt(const __hip_bfloat16* __restrict__ A,
             const __hip_bfloat16* __restrict__ Bm,
             ushort* __restrict__ Cb,
             float* __restrict__ Cf,
             ushort* __restrict__ Vt,
             int M, int N, int K) {
    constexpr int BM = 128, BN = 128, BK = 32, LDT = 32;
    __shared__ __hip_bfloat16 As[BM * LDT];
    __shared__ __hip_bfloat16 Bs[BN * LDT];

    const int tid  = threadIdx.x;
    const int lane = tid & 63;
    const int wave = tid >> 6;
    const int wr = (wave >> 1) * 64;
    const int wc = (wave & 1) * 64;
    const int quad = lane >> 4;
    const int l16  = lane & 15;

    const int row0 = blockIdx.y * BM;
    const int col0 = blockIdx.x * BN;

    const int srow = lane >> 2;          // 0..15
    const int scol = (lane & 3) * 8;     // 0,8,16,24

    f32x4 acc[4][4];
#pragma unroll
    for (int i = 0; i < 4; i++)
#pragma unroll
        for (int j = 0; j < 4; j++) acc[i][j] = (f32x4)0.0f;

    for (int k0 = 0; k0 < K; k0 += BK) {
#pragma unroll
        for (int c = 0; c < 2; c++) {
            const int seg = wave * 2 + c;           // 0..7
            const int r = seg * 16 + srow;          // 0..127
            gload_lds16(A  + (size_t)(row0 + r) * K + k0 + scol, As + seg * 512);
            gload_lds16(Bm + (size_t)(col0 + r) * K + k0 + scol, Bs + seg * 512);
        }
        __syncthreads();

        bf16x8 af[4], bfr[4];
#pragma unroll
        for (int t = 0; t < 4; t++) {
            af[t]  = load16(&As[(wr + t * 16 + l16) * LDT + quad * 8]);
            bfr[t] = load16(&Bs[(wc + t * 16 + l16) * LDT + quad * 8]);
        }
#pragma unroll
        for (int i = 0; i < 4; i++)
#pragma unroll
            for (int j = 0; j < 4; j++)
                acc[i][j] = MFMA16(af[i], bfr[j], acc[i][j]);
        __syncthreads();
    }

    if constexpr (MODE == 2) {
        if (col0 >= 2 * DMODEL) {
            // V block: transpose 128x128 C-tile in LDS, write V^T coalesced.
            __shared__ ushort Ts[64 * 136];
            const int vcol0 = col0 - 2 * DMODEL;
            const int bb = row0 >> 11;          // batch
            const int row0m = row0 & 2047;      // s offset within batch
#pragma unroll
            for (int half = 0; half < 2; half++) {
                if ((wave & 1) == half) {
#pragma unroll
                    for (int i = 0; i < 4; i++)
#pragma unroll
                        for (int j = 0; j < 4; j++) {
                            int c = j * 16 + l16;
                            int rb = wr + i * 16 + quad * 4;
#pragma unroll
                            for (int r = 0; r < 4; r++)
                                Ts[c * 136 + rb + r] = f2bf(acc[i][j][r]);
                        }
                }
                __syncthreads();
                int col = tid >> 2, part = tid & 3;
                int hh = (vcol0 >> 6) + half;
                ushort* dp = Vt + (((size_t)(bb * NHEAD + hh)) * HDIM + col) * SEQ
                                + row0m + part * 32;
                const ushort* sp = &Ts[col * 136 + part * 32];
#pragma unroll
                for (int k = 0; k < 4; k++)
                    *(uint4*)(dp + k * 8) = *(const uint4*)(sp + k * 8);
                __syncthreads();
            }
            return;
        }
    }

    ushort* base = nullptr;
    int c0 = 0;
    if constexpr (MODE == 2) {
        base = Cb + ((col0 >= DMODEL) ? (size_t)MROWS * DMODEL : 0);
        c0 = col0 & (DMODEL - 1);
    }
#pragma unroll
    for (int i = 0; i < 4; i++) {
#pragma unroll
        for (int r = 0; r < 4; r++) {
            size_t grow = (size_t)(row0 + wr + i * 16 + quad * 4 + r);
#pragma unroll
            for (int j = 0; j < 4; j++) {
                float v = acc[i][j][r];
                if (MODE == 1) {
                    Cf[grow * N + col0 + wc + j * 16 + l16] = v;
                } else {
                    base[grow * DMODEL + c0 + wc + j * 16 + l16] = f2bf(v);
                }
            }
        }
    }
}

// ---------------- flash attention, causal, ONE WAVE PER BLOCK (LPT refill) ----------------
// 4096 single-wave workgroups, longest-first. Wave owns 32 q-rows (pair p);
// 32-key chunks; K/V fragments feed both strips; row-sum via ones-MFMA.
// SWAPPED QK^T: z^T = mfma(K,Q) puts q lane-local -> P pairs are key-contiguous
// -> v_cvt_pk_bf16_f32 + 2x ds_write_b64 replace 8x f2bf + 8x ds_write_u16.
__global__ __launch_bounds__(64)
void attn_kernel(const ushort* __restrict__ Qb, const ushort* __restrict__ Kb,
                 const ushort* __restrict__ Vtb, ushort* __restrict__ O) {
    constexpr int LDP = 40;                       // 16 rows x 32 keys + 8 pad
    __shared__ ushort Pld[16 * LDP];

    const int lane = threadIdx.x & 63;
    const int quad = lane >> 4;
    const int l16  = lane & 15;

    const int blk = (int)blockIdx.x;              // 4096 blocks
    const int bh  = blk & 63;
    const int p   = 63 - (blk >> 6);              // longest pairs dispatch first
    const int b = bh >> 4, h = bh & 15;
    const int q0 = p * 32;

    // ones B-fragment for the l-sum MFMA (bf16 1.0 = 0x3F80)
    bf16x8 ones;
#pragma unroll
    for (int i = 0; i < 8; i++) ones[i] = (short)0x3F80;

    // Q fragments for both strips; Wq pre-scaled by 0.125*log2(e)
    bf16x8 qf[2][2];
#pragma unroll
    for (int s = 0; s < 2; s++) {
        const __hip_bfloat16* qp = (const __hip_bfloat16*)Qb
            + ((size_t)b * SEQ + q0 + s * 16 + l16) * DMODEL + h * HDIM;
        qf[s][0] = load16(qp + quad * 8);
        qf[s][1] = load16(qp + 32 + quad * 8);
    }

    const __hip_bfloat16* kbase = (const __hip_bfloat16*)Kb + (size_t)b * SEQ * DMODEL + h * HDIM;
    const __hip_bfloat16* vbase = (const __hip_bfloat16*)Vtb + (size_t)bh * HDIM * SEQ;

    f32x4 oacc[2][4], lacc[2];
#pragma unroll
    for (int s = 0; s < 2; s++) {
        lacc[s] = (f32x4)0.0f;
#pragma unroll
        for (int t = 0; t < 4; t++) oacc[s][t] = (f32x4)0.0f;
    }

    const int nc = p + 1;                          // 32-key chunks
    for (int c = 0; c < nc; ++c) {
        const int k0 = c * 32;
        const bool diag = (c == nc - 1);

        // K fragments: 2 S-tiles x 2 d-halves; V^T fragments: 4 d-tiles (32 keys)
        bf16x8 kb[2][2], vb[4];
#pragma unroll
        for (int t = 0; t < 2; t++) {
            const __hip_bfloat16* kp = kbase + (size_t)(k0 + t * 16 + l16) * DMODEL + quad * 8;
            kb[t][0] = load16(kp);
            kb[t][1] = load16(kp + 32);
        }
#pragma unroll
        for (int t = 0; t < 4; t++)
            vb[t] = load16(vbase + (size_t)(t * 16 + l16) * SEQ + k0 + quad * 8);

        // per strip: S^T -> exp2 -> cvt_pk -> P(LDS, b64) -> PV
#pragma unroll
        for (int s = 0; s < 2; s++) {
            // z[t][r] = S[key = k0 + t*16 + quad*4 + r, q = q0 + s*16 + l16]
            f32x4 z[2];
#pragma unroll
            for (int t = 0; t < 2; t++) {
                f32x4 zz = (f32x4)0.0f;
                zz = MFMA16(kb[t][0], qf[s][0], zz);
                zz = MFMA16(kb[t][1], qf[s][1], zz);
                z[t] = zz;
            }

#pragma unroll
            for (int t = 0; t < 2; t++) {
                float e[4];
#pragma unroll
                for (int r = 0; r < 4; r++) {
                    float sv = z[t][r];
                    if (diag) {
                        int key = k0 + t * 16 + quad * 4 + r;
                        int qq  = q0 + s * 16 + l16;
                        sv = (key <= qq) ? sv : -1e30f;
                    }
                    e[r] = exp2f(sv);
                }
                // Pld[q = l16][key = t*16 + quad*4 + r] — 4 keys contiguous -> b64
                uint2 w;
                w.x = cvt_pk_bf16(e[0], e[1]);
                w.y = cvt_pk_bf16(e[2], e[3]);
                *(uint2*)&Pld[l16 * LDP + t * 16 + quad * 4] = w;
            }
            bf16x8 pa = load16((const __hip_bfloat16*)&Pld[l16 * LDP + quad * 8]);

#pragma unroll
            for (int t = 0; t < 4; t++)
                oacc[s][t] = MFMA16(pa, vb[t], oacc[s][t]);
            lacc[s] = MFMA16(pa, ones, lacc[s]);      // row-sum via matrix pipe
        }
    }

    // normalize + store O as bf16 [B*S, D] at head offset
#pragma unroll
    for (int s = 0; s < 2; s++) {
        float inv[4];
#pragma unroll
        for (int r = 0; r < 4; r++) inv[r] = 1.0f / lacc[s][r];
#pragma unroll
        for (int t = 0; t < 4; t++) {
#pragma unroll
            for (int r = 0; r < 4; r++) {
                float v = oacc[s][t][r] * inv[r];
                O[((size_t)b * SEQ + q0 + s * 16 + quad * 4 + r) * DMODEL
                  + h * HDIM + t * 16 + l16] = f2bf(v);
            }
        }
    }
}

extern "C" void kernel_launch(void* const* d_in, const int* in_sizes, int n_in,
                              void* d_out, int out_size, void* d_ws, size_t ws_size,
                              hipStream_t stream) {
    const float* x      = (const float*)d_in[0];
    const float* w_attn = (const float*)d_in[1];
    const float* w_proj = (const float*)d_in[2];
    float* out = (float*)d_out;

    // workspace (bf16 elems): x | w_attn | w_proj | qkv{Q|K|V^T} | o
    ushort* ws   = (ushort*)d_ws;
    ushort* xb   = ws;
    ushort* wab  = xb  + (size_t)MROWS * DMODEL;
    ushort* wpb  = wab + (size_t)N_QKV * DMODEL;
    ushort* qkvb = wpb + (size_t)DMODEL * DMODEL;
    ushort* ob   = qkvb + (size_t)MROWS * N_QKV;

    ushort* qreg = qkvb;
    ushort* kreg = qkvb + (size_t)MROWS * DMODEL;
    ushort* vtreg = qkvb + 2 * (size_t)MROWS * DMODEL;

    const int n_x  = MROWS * DMODEL;
    const int n_wa = N_QKV * DMODEL;
    const int n_wp = DMODEL * DMODEL;

    const float qsc = 0.125f * 1.44269504f;  // softmax scale * log2(e) folded into W_q

    cast_bf16_kernel<<<n_x / 1024, 256, 0, stream>>>(x, xb, n_x, 0, 1.0f);
    cast_bf16_kernel<<<n_wa / 1024, 256, 0, stream>>>(w_attn, wab, n_wa,
                                                      DMODEL * DMODEL, qsc);
    cast_bf16_kernel<<<n_wp / 1024, 256, 0, stream>>>(w_proj, wpb, n_wp, 0, 1.0f);

    // qkv = x @ w_attn^T -> Q | K | V^T regions
    gemm_bt<2><<<dim3(N_QKV / 128, MROWS / 128), 256, 0, stream>>>(
        (const __hip_bfloat16*)xb, (const __hip_bfloat16*)wab, qreg, nullptr, vtreg,
        MROWS, N_QKV, DMODEL);

    // flash attention -> o (one wave per block, LPT order, HW refill)
    attn_kernel<<<4096, 64, 0, stream>>>(qreg, kreg, vtreg, ob);

    // out = o @ w_proj^T   [8192,1024] f32
    gemm_bt<1><<<dim3(DMODEL / 128, MROWS / 128), 256, 0, stream>>>(
        (const __hip_bfloat16*)ob, (const __hip_bfloat16*)wpb, nullptr, out, nullptr,
        MROWS, DMODEL, DMODEL);
}